// Round 10
// baseline (347.123 us; speedup 1.0000x reference)
//
#include <hip/hip_runtime.h>

// Depthwise 5x5 SAME conv + gate residual: out = x*(alpha*conv + bias) + x
// x: (B=32, H=112, W=112, C=96) f32 NHWC. kernel: (5,5,96) f32.
//
// R10: dual-state H-walk. Evidence from R1-R9: perf tracks TOTAL WAVES
// (5376->100-110us, 10752->91.7, 16128->90.4); per-wave in-flight is stuck
// at one row of taps because the compiler sinks register prefetch (R4/R6/
// R7). So: latency-bound, concurrency-capped. Fix = 2x MLP per wave:
//  - Each thread runs TWO independent ring-accumulator walks (adjacent
//    19-row chunks A and B of one 38-row span; same w, same c -> shared
//    weights + shared clamped tap offsets). Each iteration issues 10
//    independent scalar loads (2 rows x 5 taps) before 50 FMAs; taps are
//    consumed in-iteration so there is nothing to sink or spill.
//  - 16128 waves (scalar c-per-lane layout kept from R3, the best round).
//  - Nontemporal stores: out is never re-read; keep it out of L3 so x
//    (154 MB) stays resident -> halo re-reads stay on-die.
//  - Proven R1/R3 ring math, per state. W edges: clamped toff + zeroed
//    weight columns (proven R5/R9). H edges: uniform branch, zero-fill.

#define CHN   96
#define WI    112
#define HI    112
#define NB    32
#define NPAIR 3
#define PROWS 38                 // rows per thread (A 19 + B 19; last B 17)
#define AROWS 19
#define NIT   (AROWS + 4)        // 23 iterations
#define ROW   (WI * CHN)         // 10752 floats
#define IMG   ((size_t)HI * ROW)

__global__ __launch_bounds__(256, 6) void dwconv_gate_pair(
    const float* __restrict__ x,
    const float* __restrict__ kern,
    const float* __restrict__ alpha,
    const float* __restrict__ bias,
    float* __restrict__ out)
{
    const int gid = blockIdx.x * blockDim.x + threadIdx.x;
    // gid -> (b, pair, w, c); c innermost for coalescing
    const int c    = gid % CHN;
    const int r1   = gid / CHN;
    const int w    = r1 % WI;
    const int r2   = r1 / WI;
    const int pair = r2 % NPAIR;
    const int b    = r2 / NPAIR;
    if (b >= NB) return;

    const float av = alpha[0];
    const float bv = bias[0];

    // Clamped tap offsets; invalid dx columns killed via zeroed weights.
    int toff[5];
    bool mok[5];
#pragma unroll
    for (int dx = 0; dx < 5; ++dx) {
        const int ww = w + dx - 2;
        mok[dx] = (ww >= 0) && (ww < WI);
        const int wc = ww < 0 ? 0 : (ww >= WI ? WI - 1 : ww);
        toff[dx] = (wc - w) * CHN;
    }
    float wt[25];
#pragma unroll
    for (int i = 0; i < 25; ++i)
        wt[i] = mok[i % 5] ? kern[i * CHN + c] : 0.f;

    const int hA    = pair * PROWS;                       // A: [hA, hA+19)
    const int hB    = hA + AROWS;                         // B: [hB, hB+rowsB)
    const int rowsB = (pair == NPAIR - 1) ? (HI - hB) : AROWS;  // 19/19/17

    const float* px = x   + (size_t)b * IMG + (size_t)w * CHN + c;
    float*       po = out + (size_t)b * IMG + (size_t)w * CHN + c;

    // Per-state ring: a?[j] = partial for output row (input_row - 2 + j).
    float aA[5] = {0.f, 0.f, 0.f, 0.f, 0.f};
    float aB[5] = {0.f, 0.f, 0.f, 0.f, 0.f};
    float xA1 = 0.f, xA2 = 0.f, xB1 = 0.f, xB2 = 0.f;  // center-tap delay-2

    for (int i = 0; i < NIT; ++i) {
        const int rA = hA - 2 + i;   // <0 only for pair 0, i<2; never >=HI
        const int rB = hB - 2 + i;   // >=HI only for pair 2, i>=19; never <0
        const float* pA = px + (ptrdiff_t)rA * ROW;
        const float* pB = px + (ptrdiff_t)rB * ROW;

        // 10 independent loads at iteration top (block-uniform branches).
        float tA[5], tB[5];
        if (rA >= 0) {
            tA[0] = pA[toff[0]]; tA[1] = pA[toff[1]]; tA[2] = pA[toff[2]];
            tA[3] = pA[toff[3]]; tA[4] = pA[toff[4]];
        } else {
            tA[0] = 0.f; tA[1] = 0.f; tA[2] = 0.f; tA[3] = 0.f; tA[4] = 0.f;
        }
        if (rB < HI) {
            tB[0] = pB[toff[0]]; tB[1] = pB[toff[1]]; tB[2] = pB[toff[2]];
            tB[3] = pB[toff[3]]; tB[4] = pB[toff[4]];
        } else {
            tB[0] = 0.f; tB[1] = 0.f; tB[2] = 0.f; tB[3] = 0.f; tB[4] = 0.f;
        }

        // 50 FMAs: input row r feeds output r-2+j with weight row (4-j).
#pragma unroll
        for (int d = 0; d < 5; ++d) {
            aA[0] = fmaf(tA[d], wt[20 + d], aA[0]);
            aB[0] = fmaf(tB[d], wt[20 + d], aB[0]);
            aA[1] = fmaf(tA[d], wt[15 + d], aA[1]);
            aB[1] = fmaf(tB[d], wt[15 + d], aB[1]);
            aA[2] = fmaf(tA[d], wt[10 + d], aA[2]);
            aB[2] = fmaf(tB[d], wt[10 + d], aB[2]);
            aA[3] = fmaf(tA[d], wt[ 5 + d], aA[3]);
            aB[3] = fmaf(tB[d], wt[ 5 + d], aB[3]);
            aA[4] = fmaf(tA[d], wt[ 0 + d], aA[4]);
            aB[4] = fmaf(tB[d], wt[ 0 + d], aB[4]);
        }

        // Emit output rows (hA-4+i) / (hB-4+i) once their windows close.
        if (i >= 4) {
            const float oA = fmaf(fmaf(aA[0], av, bv), xA2, xA2);
            __builtin_nontemporal_store(oA, po + (ptrdiff_t)(hA - 4 + i) * ROW);
            if (i - 4 < rowsB) {
                const float oB = fmaf(fmaf(aB[0], av, bv), xB2, xB2);
                __builtin_nontemporal_store(oB, po + (ptrdiff_t)(hB - 4 + i) * ROW);
            }
        }

        // Static ring shifts.
        xA2 = xA1; xA1 = tA[2];
        xB2 = xB1; xB1 = tB[2];
        aA[0] = aA[1]; aA[1] = aA[2]; aA[2] = aA[3]; aA[3] = aA[4]; aA[4] = 0.f;
        aB[0] = aB[1]; aB[1] = aB[2]; aB[2] = aB[3]; aB[3] = aB[4]; aB[4] = 0.f;
    }
}

extern "C" void kernel_launch(void* const* d_in, const int* in_sizes, int n_in,
                              void* d_out, int out_size, void* d_ws, size_t ws_size,
                              hipStream_t stream) {
    const float* x     = (const float*)d_in[0];
    const float* kern  = (const float*)d_in[1];
    const float* alpha = (const float*)d_in[2];
    const float* bias  = (const float*)d_in[3];
    float* out = (float*)d_out;

    const int total = NB * NPAIR * WI * CHN;   // 1,032,192 = 4032 * 256
    dim3 block(256);
    dim3 grid(total / 256);                    // 4032 blocks, 16128 waves
    hipLaunchKernelGGL(dwconv_gate_pair, grid, block, 0, stream,
                       x, kern, alpha, bias, out);
}

// Round 11
// 85.279 us; speedup vs baseline: 4.0705x; 4.0705x over previous
//
#include <hip/hip_runtime.h>

// Depthwise 5x5 SAME conv + gate residual: out = x*(alpha*conv + bias) + x
// x: (B=32, H=112, W=112, C=96) f32 NHWC. kernel: (5,5,96) f32.
//
// R11 = R3 (best: 90.4us, VGPR=40, no spill) + ONE change:
//  - __builtin_nontemporal_store for the output. out (150 MB) is never
//    re-read; without NT it evicts x (154 MB) from the 256 MB L3 every
//    replay (304 MB > 256 MB). With NT, x stays L3-resident across timed
//    replays -> HBM fetch drops toward halo-only and reads are served at
//    L3 bandwidth. (R5's FETCH=138MB < input proved partial x residency
//    already happens even WITH write pollution.)
// Everything else is byte-identical to R3: NSPLIT=3 uneven chunks
// (38/38/36), depth-1 row prefetch ping-pong, scalar c-per-lane layout.

#define CH 96
#define WI 112
#define HI 112
#define BATCH 32
#define NSPLIT 3
#define CHUNK_ROWS 38               // chunks: 38, 38, 36
#define ROW_STRIDE (WI * CH)        // 10752
#define IMG_STRIDE (HI * WI * CH)   // 1204224

__global__ __launch_bounds__(256) void dwconv_gate_kernel(
    const float* __restrict__ x,
    const float* __restrict__ kern,
    const float* __restrict__ alpha,
    const float* __restrict__ bias,
    float* __restrict__ out)
{
    const int gid = blockIdx.x * blockDim.x + threadIdx.x;
    // gid -> (b, chunk, w, c); c innermost for coalescing
    const int c     = gid % CH;
    const int r1    = gid / CH;
    const int w     = r1 % WI;
    const int r2    = r1 / WI;
    const int chunk = r2 % NSPLIT;
    const int b     = r2 / NSPLIT;
    if (b >= BATCH) return;

    const float alphav = alpha[0];
    const float biasv  = bias[0];

    // Per-channel 5x5 weights into registers (statically indexed).
    float wt[25];
#pragma unroll
    for (int i = 0; i < 25; ++i) wt[i] = kern[i * CH + c];

    // Loop-invariant width-edge masks.
    bool mok[5];
#pragma unroll
    for (int dx = 0; dx < 5; ++dx) {
        const int ww = w + dx - 2;
        mok[dx] = (ww >= 0) && (ww < WI);
    }

    const int h0   = chunk * CHUNK_ROWS;
    const int rows = (chunk == NSPLIT - 1) ? (HI - h0) : CHUNK_ROWS; // 38/38/36
    const int nit  = rows + 4;

    const float* px = x   + (size_t)b * IMG_STRIDE + (size_t)w * CH + c;
    float*       po = out + (size_t)b * IMG_STRIDE + (size_t)w * CH + c;

    // acc[j]: partial sum for output row rin-2+j at start of the iteration
    // that processes input row rin.
    float acc[5] = {0.f, 0.f, 0.f, 0.f, 0.f};
    float xp1 = 0.f, xp2 = 0.f;   // center-tap history (delay 2) for residual
    float t[5];

    // Preload first input row (h0 - 2).
    {
        const int rin = h0 - 2;
        const bool rok = (rin >= 0);           // rin < HI always holds here
        const float* prow = px + (ptrdiff_t)rin * ROW_STRIDE;
#pragma unroll
        for (int dx = 0; dx < 5; ++dx)
            t[dx] = (rok && mok[dx]) ? prow[(dx - 2) * CH] : 0.f;
    }

    for (int i = 0; i < nit; ++i) {
        // ---- prefetch next input row (independent of the FMAs below) ----
        float tn[5];
        {
            const int rn  = h0 - 1 + i;        // (h0-2) + (i+1)
            const bool rok = (rn >= 0) && (rn < HI) && (i + 1 < nit);
            const float* prow = px + (ptrdiff_t)rn * ROW_STRIDE;
#pragma unroll
            for (int dx = 0; dx < 5; ++dx)
                tn[dx] = (rok && mok[dx]) ? prow[(dx - 2) * CH] : 0.f;
        }

        // ---- 25 FMAs on the row loaded LAST iteration (regs ready) ----
#pragma unroll
        for (int j = 0; j < 5; ++j) {
#pragma unroll
            for (int dx = 0; dx < 5; ++dx)
                acc[j] = fmaf(t[dx], wt[(4 - j) * 5 + dx], acc[j]);
        }

        // ---- emit output row (h0 - 4 + i) once its window is complete ----
        if (i >= 4) {
            const float xc = xp2;              // x center of the output row
            const float g  = fmaf(acc[0], alphav, biasv);
            __builtin_nontemporal_store(
                fmaf(g, xc, xc),
                po + (ptrdiff_t)(h0 - 4 + i) * ROW_STRIDE);
        }

        // ---- static ring shifts (stay in VGPRs) ----
        xp2 = xp1;
        xp1 = t[2];
        acc[0] = acc[1];
        acc[1] = acc[2];
        acc[2] = acc[3];
        acc[3] = acc[4];
        acc[4] = 0.f;
#pragma unroll
        for (int dx = 0; dx < 5; ++dx) t[dx] = tn[dx];  // vmcnt waits here,
                                                        // AFTER the FMAs
    }
}

extern "C" void kernel_launch(void* const* d_in, const int* in_sizes, int n_in,
                              void* d_out, int out_size, void* d_ws, size_t ws_size,
                              hipStream_t stream) {
    const float* x     = (const float*)d_in[0];
    const float* kern  = (const float*)d_in[1];
    const float* alpha = (const float*)d_in[2];
    const float* bias  = (const float*)d_in[3];
    float* out = (float*)d_out;

    const int total = BATCH * NSPLIT * WI * CH;   // 1,032,192 = 4032 * 256
    dim3 block(256);
    dim3 grid(total / 256);                       // 4032 blocks, 16128 waves
    hipLaunchKernelGGL(dwconv_gate_kernel, grid, block, 0, stream,
                       x, kern, alpha, bias, out);
}